// Round 1
// baseline (4404.101 us; speedup 1.0000x reference)
//
#include <hip/hip_runtime.h>
#include <math.h>

// ---------------------------------------------------------------------------
// Former transformer block, fp32 baseline (round 0, correctness-first).
//   D=1024, H=16, DH=64, E=2, batch n=8, seq m=1024  -> rows M = 8192
// Workspace layout (needs 192 MiB):
//   [0,96M)    qvk [8192,3072]            ... later reused:
//   [0,32M)      vh, [32M,64M) att_pre, [64M,96M) att
//   [96M,192M) q,k,v [8192,1024] each     ... later reused:
//   [96M,160M)   hidden [8192,2048], [160M,192M) out_pre
// ---------------------------------------------------------------------------

#define D_MODEL 1024
#define NHEAD   16
#define DHEAD   64
#define SEQ     1024

// ------------------------- generic fp32 GEMM -------------------------------
// C[M,N] = act(A[M,K] @ W[K,N] + bias[N]);  A has row stride lda.
// BM=BN=64, BK=16, 256 threads, 4x4 per thread. ACT: 0 none, 1 ReLU6.
template <int ACT>
__global__ __launch_bounds__(256) void gemm_f32(
    const float* __restrict__ A, int lda,
    const float* __restrict__ W,
    const float* __restrict__ bias,
    float* __restrict__ C, int ldc,
    int M, int N, int K)
{
    __shared__ float As[16][68];   // transposed: As[k][m]
    __shared__ float Bs[16][68];

    const int tx = threadIdx.x, ty = threadIdx.y;      // 16 x 16
    const int tid = ty * 16 + tx;
    const int row0 = blockIdx.y * 64;
    const int col0 = blockIdx.x * 64;

    const int ar  = tid >> 2;
    const int ac4 = (tid & 3) * 4;
    const int br  = tid >> 4;
    const int bc4 = (tid & 15) * 4;

    float c[4][4] = {};

    for (int k0 = 0; k0 < K; k0 += 16) {
        float4 av = *reinterpret_cast<const float4*>(
            &A[(size_t)(row0 + ar) * lda + k0 + ac4]);
        float4 bv = *reinterpret_cast<const float4*>(
            &W[(size_t)(k0 + br) * N + col0 + bc4]);
        As[ac4 + 0][ar] = av.x;
        As[ac4 + 1][ar] = av.y;
        As[ac4 + 2][ar] = av.z;
        As[ac4 + 3][ar] = av.w;
        *reinterpret_cast<float4*>(&Bs[br][bc4]) = bv;
        __syncthreads();

#pragma unroll
        for (int kk = 0; kk < 16; ++kk) {
            float a[4], b[4];
#pragma unroll
            for (int i = 0; i < 4; ++i) a[i] = As[kk][ty * 4 + i];
#pragma unroll
            for (int j = 0; j < 4; ++j) b[j] = Bs[kk][tx * 4 + j];
#pragma unroll
            for (int i = 0; i < 4; ++i)
#pragma unroll
                for (int j = 0; j < 4; ++j)
                    c[i][j] = fmaf(a[i], b[j], c[i][j]);
        }
        __syncthreads();
    }

    float4 bvec = *reinterpret_cast<const float4*>(&bias[col0 + tx * 4]);
    const float bb[4] = {bvec.x, bvec.y, bvec.z, bvec.w};
#pragma unroll
    for (int i = 0; i < 4; ++i) {
        const int row = row0 + ty * 4 + i;
        float v0 = c[i][0] + bb[0], v1 = c[i][1] + bb[1];
        float v2 = c[i][2] + bb[2], v3 = c[i][3] + bb[3];
        if (ACT == 1) {
            v0 = fminf(fmaxf(v0, 0.f), 6.f);
            v1 = fminf(fmaxf(v1, 0.f), 6.f);
            v2 = fminf(fmaxf(v2, 0.f), 6.f);
            v3 = fminf(fmaxf(v3, 0.f), 6.f);
        }
        float4 o; o.x = v0; o.y = v1; o.z = v2; o.w = v3;
        *reinterpret_cast<float4*>(&C[(size_t)row * ldc + col0 + tx * 4]) = o;
    }
}

// ------------------------- flash attention (fp32) --------------------------
// q/k/v: [n*SEQ, D], element (row, d*16+h).  vh: element (row, h*64+d).
// One block per (q_tile=64, head, batch); thread (r=tid>>2, cq=tid&3) owns
// S/P cols and O dims [cq*16, cq*16+16) of q-row r.  K LDS buffer reused as P.
__global__ __launch_bounds__(256) void attn_f32(
    const float* __restrict__ q,
    const float* __restrict__ k,
    const float* __restrict__ v,
    float* __restrict__ vh)
{
    __shared__ float Qs[64][65];
    __shared__ float KPs[64][65];
    __shared__ float Vs[64][64];

    const int qt = blockIdx.x;
    const int h  = blockIdx.y;
    const int n  = blockIdx.z;

    const int tid = threadIdx.x;
    const int r  = tid >> 2;
    const int cq = tid & 3;
    const float scale = 0.125f;  // 1/(sqrt(64)+1e-10)

    const size_t base = (size_t)n * SEQ * D_MODEL;

    for (int idx = tid; idx < 64 * 64; idx += 256) {
        const int rr = idx >> 6, d = idx & 63;
        Qs[rr][d] = q[base + (size_t)(qt * 64 + rr) * D_MODEL + d * NHEAD + h];
    }

    float O[16];
#pragma unroll
    for (int j = 0; j < 16; ++j) O[j] = 0.f;
    float m_run = -INFINITY, l_run = 0.f;

    for (int kt = 0; kt < 16; ++kt) {
        __syncthreads();
        for (int idx = tid; idx < 64 * 64; idx += 256) {
            const int rr = idx >> 6, d = idx & 63;
            const size_t g = base + (size_t)(kt * 64 + rr) * D_MODEL + d * NHEAD + h;
            KPs[rr][d] = k[g];
            Vs[rr][d]  = v[g];
        }
        __syncthreads();

        float s[16];
#pragma unroll
        for (int kk = 0; kk < 16; ++kk) {
            const int kc = cq * 16 + kk;
            float acc = 0.f;
#pragma unroll 8
            for (int d = 0; d < 64; ++d)
                acc = fmaf(Qs[r][d], KPs[kc][d], acc);
            s[kk] = acc * scale;
        }

        float tmax = s[0];
#pragma unroll
        for (int kk = 1; kk < 16; ++kk) tmax = fmaxf(tmax, s[kk]);
        tmax = fmaxf(tmax, __shfl_xor(tmax, 1, 64));
        tmax = fmaxf(tmax, __shfl_xor(tmax, 2, 64));

        const float m_new = fmaxf(m_run, tmax);
        const float corr  = __expf(m_run - m_new);

        float p[16], lsum = 0.f;
#pragma unroll
        for (int kk = 0; kk < 16; ++kk) {
            p[kk] = __expf(s[kk] - m_new);
            lsum += p[kk];
        }
        lsum += __shfl_xor(lsum, 1, 64);
        lsum += __shfl_xor(lsum, 2, 64);
        l_run = l_run * corr + lsum;
        m_run = m_new;

        __syncthreads();
#pragma unroll
        for (int kk = 0; kk < 16; ++kk) KPs[r][cq * 16 + kk] = p[kk];
#pragma unroll
        for (int j = 0; j < 16; ++j) O[j] *= corr;
        __syncthreads();

#pragma unroll 4
        for (int kk2 = 0; kk2 < 64; ++kk2) {
            const float pv = KPs[r][kk2];
#pragma unroll
            for (int j = 0; j < 16; ++j)
                O[j] = fmaf(pv, Vs[kk2][cq * 16 + j], O[j]);
        }
    }

    const float inv_l = 1.0f / l_run;
    float* dst = &vh[base + (size_t)(qt * 64 + r) * D_MODEL + h * 64 + cq * 16];
#pragma unroll
    for (int j4 = 0; j4 < 4; ++j4) {
        float4 o;
        o.x = O[j4 * 4 + 0] * inv_l;
        o.y = O[j4 * 4 + 1] * inv_l;
        o.z = O[j4 * 4 + 2] * inv_l;
        o.w = O[j4 * 4 + 3] * inv_l;
        *reinterpret_cast<float4*>(dst + j4 * 4) = o;
    }
}

// ------------------------------ LayerNorm ----------------------------------
__global__ __launch_bounds__(256) void layernorm_f32(
    const float* __restrict__ x,
    const float* __restrict__ g,
    const float* __restrict__ b,
    float* __restrict__ out)
{
    const int row = blockIdx.x;
    const int tid = threadIdx.x;

    const float4 xv = *reinterpret_cast<const float4*>(
        &x[(size_t)row * 1024 + tid * 4]);
    float s  = xv.x + xv.y + xv.z + xv.w;
    float sq = xv.x * xv.x + xv.y * xv.y + xv.z * xv.z + xv.w * xv.w;

#pragma unroll
    for (int off = 1; off < 64; off <<= 1) {
        s  += __shfl_xor(s,  off, 64);
        sq += __shfl_xor(sq, off, 64);
    }
    __shared__ float ls[4], lq[4];
    const int wave = tid >> 6;
    if ((tid & 63) == 0) { ls[wave] = s; lq[wave] = sq; }
    __syncthreads();
    s  = ls[0] + ls[1] + ls[2] + ls[3];
    sq = lq[0] + lq[1] + lq[2] + lq[3];

    const float mu  = s * (1.0f / 1024.0f);
    const float var = sq * (1.0f / 1024.0f) - mu * mu;
    const float rs  = rsqrtf(var + 1e-5f);

    const float4 gv = *reinterpret_cast<const float4*>(&g[tid * 4]);
    const float4 bv = *reinterpret_cast<const float4*>(&b[tid * 4]);
    float4 o;
    o.x = (xv.x - mu) * rs * gv.x + bv.x;
    o.y = (xv.y - mu) * rs * gv.y + bv.y;
    o.z = (xv.z - mu) * rs * gv.z + bv.z;
    o.w = (xv.w - mu) * rs * gv.w + bv.w;
    *reinterpret_cast<float4*>(&out[(size_t)row * 1024 + tid * 4]) = o;
}

// ------------------------------- launch ------------------------------------
extern "C" void kernel_launch(void* const* d_in, const int* in_sizes, int n_in,
                              void* d_out, int out_size, void* d_ws, size_t ws_size,
                              hipStream_t stream)
{
    const float* x     = (const float*)d_in[0];
    const float* w_qvk = (const float*)d_in[1];
    const float* b_qvk = (const float*)d_in[2];
    const float* w_q   = (const float*)d_in[3];
    const float* b_q   = (const float*)d_in[4];
    const float* w_k   = (const float*)d_in[5];
    const float* b_k   = (const float*)d_in[6];
    const float* w_v   = (const float*)d_in[7];
    const float* b_v   = (const float*)d_in[8];
    const float* w_o   = (const float*)d_in[9];
    const float* b_o   = (const float*)d_in[10];
    const float* ln1_g = (const float*)d_in[11];
    const float* ln1_b = (const float*)d_in[12];
    const float* w1    = (const float*)d_in[13];
    const float* b1    = (const float*)d_in[14];
    const float* w2    = (const float*)d_in[15];
    const float* b2    = (const float*)d_in[16];
    const float* ln2_g = (const float*)d_in[17];
    const float* ln2_b = (const float*)d_in[18];
    float* out = (float*)d_out;

    const int nbatch = in_sizes[0] / (SEQ * D_MODEL);   // 8
    const int M = nbatch * SEQ;                         // 8192

    char* ws = (char*)d_ws;
    const size_t MB32 = 33554432;  // 32 MiB = 8192*1024*4
    float* qvk     = (float*)(ws);
    float* qb      = (float*)(ws + 3 * MB32);
    float* kb      = (float*)(ws + 4 * MB32);
    float* vb      = (float*)(ws + 5 * MB32);
    float* vh      = (float*)(ws);
    float* att_pre = (float*)(ws + 1 * MB32);
    float* att     = (float*)(ws + 2 * MB32);
    float* hidden  = (float*)(ws + 3 * MB32);
    float* out_pre = (float*)(ws + 5 * MB32);

    const dim3 blk(16, 16);

    gemm_f32<0><<<dim3(3072 / 64, M / 64), blk, 0, stream>>>(
        x, 1024, w_qvk, b_qvk, qvk, 3072, M, 3072, 1024);
    gemm_f32<0><<<dim3(1024 / 64, M / 64), blk, 0, stream>>>(
        qvk + 0,    3072, w_q, b_q, qb, 1024, M, 1024, 1024);
    gemm_f32<0><<<dim3(1024 / 64, M / 64), blk, 0, stream>>>(
        qvk + 1024, 3072, w_k, b_k, kb, 1024, M, 1024, 1024);
    gemm_f32<0><<<dim3(1024 / 64, M / 64), blk, 0, stream>>>(
        qvk + 2048, 3072, w_v, b_v, vb, 1024, M, 1024, 1024);

    attn_f32<<<dim3(SEQ / 64, NHEAD, nbatch), 256, 0, stream>>>(qb, kb, vb, vh);

    gemm_f32<0><<<dim3(1024 / 64, M / 64), blk, 0, stream>>>(
        vh, 1024, w_o, b_o, att_pre, 1024, M, 1024, 1024);
    layernorm_f32<<<M, 256, 0, stream>>>(att_pre, ln1_g, ln1_b, att);

    gemm_f32<1><<<dim3(2048 / 64, M / 64), blk, 0, stream>>>(
        att, 1024, w1, b1, hidden, 2048, M, 2048, 1024);
    gemm_f32<0><<<dim3(1024 / 64, M / 64), blk, 0, stream>>>(
        hidden, 2048, w2, b2, out_pre, 1024, M, 1024, 2048);
    layernorm_f32<<<M, 256, 0, stream>>>(out_pre, ln2_g, ln2_b, out);
}

// Round 8
// 627.361 us; speedup vs baseline: 7.0200x; 7.0200x over previous
//
#include <hip/hip_runtime.h>
#include <math.h>

// ---------------------------------------------------------------------------
// Former transformer block, bf16-MFMA (round 7: unchanged resubmit; GPU was
// unavailable rounds 2-7, so this design is still awaiting first measurement).
// D=1024, H=16, DH=64, E=2, n=8, seq=1024 -> M = 8192 rows.
// All GEMMs + attention on v_mfma_f32_16x16x32_bf16 (m97-style 128^2 tiles).
// q/k/v weights column-permuted at transpose-cast time so q/k/v come out
// head-contiguous ([row][h*64+d]).  V additionally transposed in global
// (vT[h*64+d][nb*1024+k]) so attention stages K and V^T identically:
// linear global_load_lds + ((row&7)<<4) byte-XOR source swizzle (m214
// pattern), conflict-free swizzled ds_read_b128 fragments.
// fp32 kept for: accumulators, bias, softmax state, LN stats, final out.
// ---------------------------------------------------------------------------

#define D_MODEL 1024
#define SEQ     1024
#define NHEAD   16

typedef short          s16x8 __attribute__((ext_vector_type(8)));
typedef unsigned short u16x4 __attribute__((ext_vector_type(4)));
typedef float          f32x4 __attribute__((ext_vector_type(4)));

__device__ __forceinline__ unsigned short f2bf(float f) {
    union { float f; unsigned u; } c; c.f = f;
    unsigned u = c.u;
    return (unsigned short)((u + 0x7FFFu + ((u >> 16) & 1u)) >> 16);  // RNE
}
__device__ __forceinline__ float bf2f(unsigned short h) {
    union { unsigned u; float f; } c; c.u = ((unsigned)h) << 16; return c.f;
}

#define GLB(p) ((const __attribute__((address_space(1))) void*)(p))
#define LDSP(p) ((__attribute__((address_space(3))) void*)(p))

// ------------------------- f32 -> bf16 cast --------------------------------
__global__ __launch_bounds__(256) void cast_f32_bf16(
    const float* __restrict__ in, unsigned short* __restrict__ out, int n4)
{
    int i = blockIdx.x * 256 + threadIdx.x;
    if (i < n4) {
        float4 v = ((const float4*)in)[i];
        u16x4 o;
        o[0] = f2bf(v.x); o[1] = f2bf(v.y); o[2] = f2bf(v.z); o[3] = f2bf(v.w);
        ((u16x4*)out)[i] = o;
    }
}

// ---------------- weight transpose-cast: W[K][N]f32 -> Wt[N][K]bf16 --------
// PERM: output row n' takes source column n = (n'&63)*16 + (n'>>6)
// (head-interleave d*16+h  ->  head-contiguous h*64+d).
template <bool PERM>
__global__ __launch_bounds__(256) void wt_cast(
    const float* __restrict__ W, unsigned short* __restrict__ Wt, int K, int N)
{
    __shared__ float T[32][33];
    const int tx = threadIdx.x, ty = threadIdx.y;        // (32, 8)
    const int nb = blockIdx.x * 32, kb = blockIdx.y * 32;
    const int nOut = nb + tx;
    const int nSrc = PERM ? (((nOut & 63) << 4) + (nOut >> 6)) : nOut;
#pragma unroll
    for (int q = 0; q < 4; ++q)
        T[ty + q * 8][tx] = W[(size_t)(kb + ty + q * 8) * N + nSrc];
    __syncthreads();
#pragma unroll
    for (int q = 0; q < 4; ++q)
        Wt[(size_t)(nb + ty + q * 8) * K + kb + tx] = f2bf(T[tx][ty + q * 8]);
}

// ------------------------- bias permute (f32) ------------------------------
__global__ void perm_bias(const float* __restrict__ in, float* __restrict__ out)
{
    int i = threadIdx.x;   // 1024
    out[i] = in[((i & 63) << 4) + (i >> 6)];
}

// ------------- global V transpose: vb[M][1024] -> vT[1024][M] --------------
// Reads coalesced (64 lanes x 2B = 128B segments); each lane writes one
// 16B run of a vT row.  16 MiB each way; L2/HBM absorbs the scatter.
__global__ __launch_bounds__(256) void transpose_v(
    const unsigned short* __restrict__ vb, unsigned short* __restrict__ vt, int M)
{
    const int T = blockIdx.x * 256 + threadIdx.x;
    const int c  = T & 1023;          // vb col = vT row (= h*64+d)
    const int r0 = (T >> 10) << 3;    // 8-row chunk of vb = 8-col chunk of vT
    s16x8 o;
#pragma unroll
    for (int i = 0; i < 8; ++i)
        o[i] = (short)vb[(size_t)(r0 + i) * 1024 + c];
    *(s16x8*)&vt[(size_t)c * M + r0] = o;
}

// ------------------------- bf16 MFMA GEMM (m97 structure) ------------------
// C[M,N] = act(A[M,K] @ Wt[N,K]^T + bias); 128x128 tile, BK=32, 4 waves,
// each wave a 64x64 quadrant as 4x4 frags of 16x16x32. ACT: 0 none, 1 ReLU6.
template <int ACT>
__global__ __launch_bounds__(256) void gemm_bf16(
    const unsigned short* __restrict__ A, int lda,
    const unsigned short* __restrict__ Bt,
    const float* __restrict__ bias,
    unsigned short* __restrict__ C, int ldc,
    int M, int N, int K)
{
    __shared__ unsigned short At[128 * 32];
    __shared__ unsigned short Bl[128 * 32];
    const int tid = threadIdx.x;
    const int w = tid >> 6, l = tid & 63, g = l >> 4, lr = l & 15;
    const int row0 = blockIdx.y * 128, col0 = blockIdx.x * 128;
    const int wr = (w >> 1) * 64, wc = (w & 1) * 64;

    f32x4 zero = {0.f, 0.f, 0.f, 0.f};
    f32x4 acc[4][4];
#pragma unroll
    for (int m = 0; m < 4; ++m)
#pragma unroll
        for (int n = 0; n < 4; ++n) acc[m][n] = zero;

    // staging: wave w stages rows [w*32, w*32+32) of each tile, 2 issues each
    const int srow = w * 32 + (l >> 2);
    const int scol = (l & 3) * 8;
    const unsigned short* aS = A + (size_t)(row0 + srow) * lda + scol;
    const unsigned short* bS = Bt + (size_t)(col0 + srow) * K + scol;
    unsigned short* aD0 = &At[w * 1024];
    unsigned short* aD1 = &At[w * 1024 + 512];
    unsigned short* bD0 = &Bl[w * 1024];
    unsigned short* bD1 = &Bl[w * 1024 + 512];

    for (int k0 = 0; k0 < K; k0 += 32) {
        __syncthreads();
        __builtin_amdgcn_global_load_lds(GLB(aS + k0), LDSP(aD0), 16, 0, 0);
        __builtin_amdgcn_global_load_lds(GLB(aS + (size_t)16 * lda + k0), LDSP(aD1), 16, 0, 0);
        __builtin_amdgcn_global_load_lds(GLB(bS + k0), LDSP(bD0), 16, 0, 0);
        __builtin_amdgcn_global_load_lds(GLB(bS + (size_t)16 * K + k0), LDSP(bD1), 16, 0, 0);
        __syncthreads();

        s16x8 a[4], b[4];
#pragma unroll
        for (int m = 0; m < 4; ++m)
            a[m] = *(const s16x8*)&At[(wr + m * 16 + lr) * 32 + g * 8];
#pragma unroll
        for (int n = 0; n < 4; ++n)
            b[n] = *(const s16x8*)&Bl[(wc + n * 16 + lr) * 32 + g * 8];
#pragma unroll
        for (int m = 0; m < 4; ++m)
#pragma unroll
            for (int n = 0; n < 4; ++n)
                acc[m][n] = __builtin_amdgcn_mfma_f32_16x16x32_bf16(
                    a[m], b[n], acc[m][n], 0, 0, 0);
    }

    float bv[4];
#pragma unroll
    for (int n = 0; n < 4; ++n) bv[n] = bias[col0 + wc + n * 16 + lr];
#pragma unroll
    for (int m = 0; m < 4; ++m)
#pragma unroll
        for (int n = 0; n < 4; ++n)
#pragma unroll
            for (int r = 0; r < 4; ++r) {
                float vv = acc[m][n][r] + bv[n];
                if (ACT == 1) vv = fminf(fmaxf(vv, 0.f), 6.f);
                const int row = row0 + wr + m * 16 + g * 4 + r;
                const int col = col0 + wc + n * 16 + lr;
                C[(size_t)row * ldc + col] = f2bf(vv);
            }
}

// ------------------------- flash attention, bf16 MFMA ----------------------
// q/k: [M][1024] bf16 head-contiguous; vt: [1024][M] bf16 (V^T).
// Block = (q-tile 64, head, batch), 4 waves; wave w owns q-rows w*16..+16.
// K and V^T tiles: linear LDS via global_load_lds, source pre-swizzled with
// byte XOR ((row&7)<<4); all fragment ds_read_b128s use the same swizzle.
// P round-trips through per-wave swizzled LDS; softmax f32 (online).
__global__ __launch_bounds__(256) void attn_mfma(
    const unsigned short* __restrict__ q,
    const unsigned short* __restrict__ k,
    const unsigned short* __restrict__ vt,
    unsigned short* __restrict__ vh, int M)
{
    __shared__ unsigned short Kt[64 * 64];   // [k-row][d]      (swizzled)
    __shared__ unsigned short Vl[64 * 64];   // [d-row][k-col]  (swizzled)
    __shared__ unsigned short Pt[4][16 * 64];

    const int tid = threadIdx.x, w = tid >> 6, l = tid & 63;
    const int g = l >> 4, lr = l & 15;
    const int qt = blockIdx.x, h = blockIdx.y, nb = blockIdx.z;

    const unsigned short* qB = q + (size_t)nb * SEQ * D_MODEL + h * 64;
    const unsigned short* kB = k + (size_t)nb * SEQ * D_MODEL + h * 64;
    const unsigned short* vB = vt + (size_t)h * 64 * M + nb * SEQ;

    // Q fragments in registers (wave's 16 q-rows)
    s16x8 qa0, qa1;
    {
        const unsigned short* qp = qB + (size_t)(qt * 64 + w * 16 + lr) * D_MODEL + g * 8;
        qa0 = *(const s16x8*)qp;
        qa1 = *(const s16x8*)(qp + 32);
    }

    f32x4 zero = {0.f, 0.f, 0.f, 0.f};
    f32x4 Oc[4];
#pragma unroll
    for (int nd = 0; nd < 4; ++nd) Oc[nd] = zero;
    float mrun[4], lrun[4];
#pragma unroll
    for (int r = 0; r < 4; ++r) { mrun[r] = -3.0e38f; lrun[r] = 0.f; }

    // staging: wave w stages rows [w*16, w*16+16) of each tile (2 issues).
    const int srow = w * 16 + (l >> 3);
    const int scol = (((l & 7) * 16) ^ (((l >> 3) & 7) << 4)) >> 1;  // elems

    for (int kt = 0; kt < 16; ++kt) {
        __syncthreads();   // all waves done reading previous Kt/Vl
        const unsigned short* ks0 = kB + (size_t)(kt * 64 + srow) * D_MODEL + scol;
        __builtin_amdgcn_global_load_lds(GLB(ks0), LDSP(&Kt[w * 1024]), 16, 0, 0);
        __builtin_amdgcn_global_load_lds(GLB(ks0 + (size_t)8 * D_MODEL),
                                         LDSP(&Kt[w * 1024 + 512]), 16, 0, 0);
        const unsigned short* vs0 = vB + (size_t)srow * M + kt * 64 + scol;
        __builtin_amdgcn_global_load_lds(GLB(vs0), LDSP(&Vl[w * 1024]), 16, 0, 0);
        __builtin_amdgcn_global_load_lds(GLB(vs0 + (size_t)8 * M),
                                         LDSP(&Vl[w * 1024 + 512]), 16, 0, 0);
        __syncthreads();   // tiles ready (barrier drains vmcnt)

        // S = Q K^T  (out rows = q-local g*4+r, cols = k-local nk*16+lr)
        f32x4 sc[4];
#pragma unroll
        for (int nk = 0; nk < 4; ++nk) {
            const int row = nk * 16 + lr;
            const int swz = (row & 7) << 4;
            const s16x8 b0 = *(const s16x8*)&Kt[row * 64 + (((g * 16) ^ swz) >> 1)];
            const s16x8 b1 = *(const s16x8*)&Kt[row * 64 + (((g * 16 + 64) ^ swz) >> 1)];
            sc[nk] = __builtin_amdgcn_mfma_f32_16x16x32_bf16(qa0, b0, zero, 0, 0, 0);
            sc[nk] = __builtin_amdgcn_mfma_f32_16x16x32_bf16(qa1, b1, sc[nk], 0, 0, 0);
        }

        // online softmax (per r: q-row g*4+r; reduce across lr lanes)
        float corr[4];
#pragma unroll
        for (int r = 0; r < 4; ++r) {
            float s0 = sc[0][r] * 0.125f, s1 = sc[1][r] * 0.125f;
            float s2 = sc[2][r] * 0.125f, s3 = sc[3][r] * 0.125f;
            float mt = fmaxf(fmaxf(s0, s1), fmaxf(s2, s3));
            mt = fmaxf(mt, __shfl_xor(mt, 1, 64));
            mt = fmaxf(mt, __shfl_xor(mt, 2, 64));
            mt = fmaxf(mt, __shfl_xor(mt, 4, 64));
            mt = fmaxf(mt, __shfl_xor(mt, 8, 64));
            const float mn = fmaxf(mrun[r], mt);
            corr[r] = __expf(mrun[r] - mn);
            mrun[r] = mn;
            float p0 = __expf(s0 - mn), p1 = __expf(s1 - mn);
            float p2 = __expf(s2 - mn), p3 = __expf(s3 - mn);
            float ps = p0 + p1 + p2 + p3;
            ps += __shfl_xor(ps, 1, 64);
            ps += __shfl_xor(ps, 2, 64);
            ps += __shfl_xor(ps, 4, 64);
            ps += __shfl_xor(ps, 8, 64);
            lrun[r] = lrun[r] * corr[r] + ps;

            const int qrow = g * 4 + r;
            const int pswz = (qrow & 7) << 4;
            Pt[w][qrow * 64 + (((2 * (0 * 16 + lr)) ^ pswz) >> 1)] = f2bf(p0);
            Pt[w][qrow * 64 + (((2 * (1 * 16 + lr)) ^ pswz) >> 1)] = f2bf(p1);
            Pt[w][qrow * 64 + (((2 * (2 * 16 + lr)) ^ pswz) >> 1)] = f2bf(p2);
            Pt[w][qrow * 64 + (((2 * (3 * 16 + lr)) ^ pswz) >> 1)] = f2bf(p3);
        }
#pragma unroll
        for (int nd = 0; nd < 4; ++nd)
#pragma unroll
            for (int r = 0; r < 4; ++r) Oc[nd][r] *= corr[r];

        // O += P V : A-frag = P (rows lr), B-frag = V^T tile (rows d)
#pragma unroll
        for (int kk = 0; kk < 2; ++kk) {
            const int prswz = (lr & 7) << 4;
            const s16x8 pa = *(const s16x8*)
                &Pt[w][lr * 64 + (((g * 16 + kk * 64) ^ prswz) >> 1)];
#pragma unroll
            for (int nd = 0; nd < 4; ++nd) {
                const int row = nd * 16 + lr;
                const int vswz = (row & 7) << 4;
                const s16x8 bv = *(const s16x8*)
                    &Vl[row * 64 + (((g * 16 + kk * 64) ^ vswz) >> 1)];
                Oc[nd] = __builtin_amdgcn_mfma_f32_16x16x32_bf16(pa, bv, Oc[nd], 0, 0, 0);
            }
        }
    }

    // epilogue: normalize, stage via Pt[w], coalesced bf16 store
    float inv[4];
#pragma unroll
    for (int r = 0; r < 4; ++r) inv[r] = 1.0f / lrun[r];
#pragma unroll
    for (int nd = 0; nd < 4; ++nd)
#pragma unroll
        for (int r = 0; r < 4; ++r) {
            const int qrow = g * 4 + r;
            const int pswz = (qrow & 7) << 4;
            Pt[w][qrow * 64 + (((2 * (nd * 16 + lr)) ^ pswz) >> 1)] =
                f2bf(Oc[nd][r] * inv[r]);
        }
    const int rr = l >> 2;
    unsigned short* dst = vh + (size_t)(nb * SEQ + qt * 64 + w * 16 + rr) * D_MODEL + h * 64;
#pragma unroll
    for (int hh = 0; hh < 2; ++hh) {
        const int sb = (l & 3) * 32 + hh * 16;
        s16x8 o = *(const s16x8*)&Pt[w][rr * 64 + ((sb ^ ((rr & 7) << 4)) >> 1)];
        *(s16x8*)(dst + (sb >> 1)) = o;
    }
}

// ------------------------------ LayerNorm (bf16 in) ------------------------
template <int OUTF32>
__global__ __launch_bounds__(256) void ln_bf16(
    const unsigned short* __restrict__ x,
    const float* __restrict__ gg,
    const float* __restrict__ bb,
    void* __restrict__ outp)
{
    const int row = blockIdx.x, tid = threadIdx.x;
    u16x4 xv = *(const u16x4*)&x[(size_t)row * 1024 + tid * 4];
    float f0 = bf2f(xv[0]), f1 = bf2f(xv[1]), f2 = bf2f(xv[2]), f3 = bf2f(xv[3]);
    float s  = f0 + f1 + f2 + f3;
    float sq = f0 * f0 + f1 * f1 + f2 * f2 + f3 * f3;
#pragma unroll
    for (int off = 1; off < 64; off <<= 1) {
        s  += __shfl_xor(s,  off, 64);
        sq += __shfl_xor(sq, off, 64);
    }
    __shared__ float ls[4], lq[4];
    const int wave = tid >> 6;
    if ((tid & 63) == 0) { ls[wave] = s; lq[wave] = sq; }
    __syncthreads();
    s  = ls[0] + ls[1] + ls[2] + ls[3];
    sq = lq[0] + lq[1] + lq[2] + lq[3];
    const float mu  = s * (1.0f / 1024.0f);
    const float var = sq * (1.0f / 1024.0f) - mu * mu;
    const float rs  = rsqrtf(var + 1e-5f);
    const float4 gv = ((const float4*)gg)[tid];
    const float4 bv = ((const float4*)bb)[tid];
    float o0 = (f0 - mu) * rs * gv.x + bv.x;
    float o1 = (f1 - mu) * rs * gv.y + bv.y;
    float o2 = (f2 - mu) * rs * gv.z + bv.z;
    float o3 = (f3 - mu) * rs * gv.w + bv.w;
    if (OUTF32) {
        float4 o; o.x = o0; o.y = o1; o.z = o2; o.w = o3;
        ((float4*)outp)[(size_t)row * 256 + tid] = o;
    } else {
        u16x4 o;
        o[0] = f2bf(o0); o[1] = f2bf(o1); o[2] = f2bf(o2); o[3] = f2bf(o3);
        ((u16x4*)outp)[(size_t)row * 256 + tid] = o;
    }
}

// ------------------------------- launch ------------------------------------
extern "C" void kernel_launch(void* const* d_in, const int* in_sizes, int n_in,
                              void* d_out, int out_size, void* d_ws, size_t ws_size,
                              hipStream_t stream)
{
    const float* x     = (const float*)d_in[0];
    const float* w_qvk = (const float*)d_in[1];
    const float* b_qvk = (const float*)d_in[2];
    const float* w_q   = (const float*)d_in[3];
    const float* b_q   = (const float*)d_in[4];
    const float* w_k   = (const float*)d_in[5];
    const float* b_k   = (const float*)d_in[6];
    const float* w_v   = (const float*)d_in[7];
    const float* b_v   = (const float*)d_in[8];
    const float* w_o   = (const float*)d_in[9];
    const float* b_o   = (const float*)d_in[10];
    const float* ln1_g = (const float*)d_in[11];
    const float* ln1_b = (const float*)d_in[12];
    const float* w1    = (const float*)d_in[13];
    const float* b1    = (const float*)d_in[14];
    const float* w2    = (const float*)d_in[15];
    const float* b2    = (const float*)d_in[16];
    const float* ln2_g = (const float*)d_in[17];
    const float* ln2_b = (const float*)d_in[18];
    float* out = (float*)d_out;

    const int nbatch = in_sizes[0] / (SEQ * D_MODEL);   // 8
    const int M = nbatch * SEQ;                          // 8192

    char* ws = (char*)d_ws;
    size_t off = 0;
    auto alloc = [&](size_t bytes) { size_t o = off; off += (bytes + 255) & ~(size_t)255; return o; };
    const size_t XB   = alloc((size_t)M * 1024 * 2);
    const size_t WQVK = alloc((size_t)3072 * 1024 * 2);
    const size_t WQ   = alloc((size_t)1024 * 1024 * 2);
    const size_t WK   = alloc((size_t)1024 * 1024 * 2);
    const size_t WV   = alloc((size_t)1024 * 1024 * 2);
    const size_t WO   = alloc((size_t)1024 * 1024 * 2);
    const size_t W1   = alloc((size_t)2048 * 1024 * 2);
    const size_t W2   = alloc((size_t)2048 * 1024 * 2);
    const size_t BQP  = alloc(4096);
    const size_t BKP  = alloc(4096);
    const size_t BVP  = alloc(4096);
    const size_t QVKB = alloc((size_t)M * 3072 * 2);     // 48 MiB
    const size_t QBUF = alloc((size_t)M * 1024 * 2);     // 16 MiB
    const size_t KBUF = alloc((size_t)M * 1024 * 2);
    const size_t VBUF = alloc((size_t)M * 1024 * 2);
    const size_t VT   = alloc((size_t)M * 1024 * 2);     // V^T [1024][M]
    // aliases into dead regions:
    const size_t VH   = QVKB;                            // [0,16M) of qvkb
    const size_t ATTP = QVKB + (size_t)M * 1024 * 2;     // [16M,32M)
    const size_t ATT  = QVKB + (size_t)M * 2048 * 2;     // [32M,48M)
    const size_t HID  = QBUF;                            // 32 MiB (qb+kb)
    const size_t OUTP = VBUF;

    unsigned short* xb   = (unsigned short*)(ws + XB);
    unsigned short* wqvk = (unsigned short*)(ws + WQVK);
    unsigned short* wq   = (unsigned short*)(ws + WQ);
    unsigned short* wk   = (unsigned short*)(ws + WK);
    unsigned short* wv   = (unsigned short*)(ws + WV);
    unsigned short* wo   = (unsigned short*)(ws + WO);
    unsigned short* wt1  = (unsigned short*)(ws + W1);
    unsigned short* wt2  = (unsigned short*)(ws + W2);
    float*          bqp  = (float*)(ws + BQP);
    float*          bkp  = (float*)(ws + BKP);
    float*          bvp  = (float*)(ws + BVP);
    unsigned short* qvkb = (unsigned short*)(ws + QVKB);
    unsigned short* qb   = (unsigned short*)(ws + QBUF);
    unsigned short* kb   = (unsigned short*)(ws + KBUF);
    unsigned short* vb   = (unsigned short*)(ws + VBUF);
    unsigned short* vtb  = (unsigned short*)(ws + VT);
    unsigned short* vhb  = (unsigned short*)(ws + VH);
    unsigned short* attp = (unsigned short*)(ws + ATTP);
    unsigned short* attb = (unsigned short*)(ws + ATT);
    unsigned short* hid  = (unsigned short*)(ws + HID);
    unsigned short* outp = (unsigned short*)(ws + OUTP);

    const dim3 tb(32, 8);

    // input cast + weight transpose-casts + bias permutes
    cast_f32_bf16<<<(M * 1024 / 4 + 255) / 256, 256, 0, stream>>>(x, xb, M * 1024 / 4);
    wt_cast<false><<<dim3(96, 32), tb, 0, stream>>>(w_qvk, wqvk, 1024, 3072);
    wt_cast<true ><<<dim3(32, 32), tb, 0, stream>>>(w_q, wq, 1024, 1024);
    wt_cast<true ><<<dim3(32, 32), tb, 0, stream>>>(w_k, wk, 1024, 1024);
    wt_cast<true ><<<dim3(32, 32), tb, 0, stream>>>(w_v, wv, 1024, 1024);
    wt_cast<false><<<dim3(32, 32), tb, 0, stream>>>(w_o, wo, 1024, 1024);
    wt_cast<false><<<dim3(64, 32), tb, 0, stream>>>(w1, wt1, 1024, 2048);
    wt_cast<false><<<dim3(32, 64), tb, 0, stream>>>(w2, wt2, 2048, 1024);
    perm_bias<<<1, 1024, 0, stream>>>(b_q, bqp);
    perm_bias<<<1, 1024, 0, stream>>>(b_k, bkp);
    perm_bias<<<1, 1024, 0, stream>>>(b_v, bvp);

    // GEMM chain
    gemm_bf16<0><<<dim3(24, M / 128), 256, 0, stream>>>(
        xb, 1024, wqvk, b_qvk, qvkb, 3072, M, 3072, 1024);
    gemm_bf16<0><<<dim3(8, M / 128), 256, 0, stream>>>(
        qvkb + 0,    3072, wq, bqp, qb, 1024, M, 1024, 1024);
    gemm_bf16<0><<<dim3(8, M / 128), 256, 0, stream>>>(
        qvkb + 1024, 3072, wk, bkp, kb, 1024, M, 1024, 1024);
    gemm_bf16<0><<<dim3(8, M / 128), 256, 0, stream>>>(
        qvkb + 2048, 3072, wv, bvp, vb, 1024, M, 1024, 1024);

    transpose_v<<<(M / 8) * 1024 / 256, 256, 0, stream>>>(vb, vtb, M);
    attn_mfma<<<dim3(SEQ / 64, NHEAD, nbatch), 256, 0, stream>>>(qb, kb, vtb, vhb, M);

    gemm_bf16<0><<<dim3(8, M / 128), 256, 0, stream>>>(
        vhb, 1024, wo, b_o, attp, 1024, M, 1024, 1024);
    ln_bf16<0><<<M, 256, 0, stream>>>(attp, ln1_g, ln1_b, attb);

    gemm_bf16<1><<<dim3(16, M / 128), 256, 0, stream>>>(
        attb, 1024, wt1, b1, hid, 2048, M, 2048, 1024);
    gemm_bf16<0><<<dim3(8, M / 128), 256, 0, stream>>>(
        hid, 2048, wt2, b2, outp, 1024, M, 1024, 2048);
    ln_bf16<1><<<M, 256, 0, stream>>>(outp, ln2_g, ln2_b, out);
}

// Round 11
// 578.656 us; speedup vs baseline: 7.6109x; 1.0842x over previous
//
#include <hip/hip_runtime.h>
#include <math.h>

// ---------------------------------------------------------------------------
// Former transformer block, bf16-MFMA (round 11: unchanged resubmit of the
// round-9 design; GPU unavailable rounds 9-10 — audits complete, awaiting
// first measurement of the fused-qkv pipeline).
// Round-8 measured baseline of this structure: 627 us, attn VALU-bound.
// Design: (1) algebraic fusion q/k/v = x @ (w_qvk_slice @ w_*) — removes
// the three 17-GF projection GEMMs; combined weights built on-device with a
// small 3-slice MFMA GEMM; bias folded by a tiny reduction kernel.
// (2) QK 0.125 scale folded into combined q-weight/bias (exact, pow2).
// (3) attn P->bf16 via v_cvt_pk_bf16_f32 (bit-identical RNE, ~3x fewer VALU).
// ---------------------------------------------------------------------------

#define D_MODEL 1024
#define SEQ     1024
#define NHEAD   16

typedef short          s16x8 __attribute__((ext_vector_type(8)));
typedef unsigned short u16x4 __attribute__((ext_vector_type(4)));
typedef float          f32x4 __attribute__((ext_vector_type(4)));

__device__ __forceinline__ unsigned short f2bf(float f) {
    union { float f; unsigned u; } c; c.f = f;
    unsigned u = c.u;
    return (unsigned short)((u + 0x7FFFu + ((u >> 16) & 1u)) >> 16);  // RNE
}
__device__ __forceinline__ float bf2f(unsigned short h) {
    union { unsigned u; float f; } c; c.u = ((unsigned)h) << 16; return c.f;
}

#define GLB(p) ((const __attribute__((address_space(1))) void*)(p))
#define LDSP(p) ((__attribute__((address_space(3))) void*)(p))

// ------------------------- f32 -> bf16 cast --------------------------------
__global__ __launch_bounds__(256) void cast_f32_bf16(
    const float* __restrict__ in, unsigned short* __restrict__ out, int n4)
{
    int i = blockIdx.x * 256 + threadIdx.x;
    if (i < n4) {
        float4 v = ((const float4*)in)[i];
        u16x4 o;
        o[0] = f2bf(v.x); o[1] = f2bf(v.y); o[2] = f2bf(v.z); o[3] = f2bf(v.w);
        ((u16x4*)out)[i] = o;
    }
}

// ---------------- weight transpose-cast: W[K][N]f32 -> Wt[N][K]bf16 --------
// PERM: output row n' takes source column n = (n'&63)*16 + (n'>>6).
template <bool PERM>
__global__ __launch_bounds__(256) void wt_cast(
    const float* __restrict__ W, unsigned short* __restrict__ Wt, int K, int N)
{
    __shared__ float T[32][33];
    const int tx = threadIdx.x, ty = threadIdx.y;        // (32, 8)
    const int nb = blockIdx.x * 32, kb = blockIdx.y * 32;
    const int nOut = nb + tx;
    const int nSrc = PERM ? (((nOut & 63) << 4) + (nOut >> 6)) : nOut;
#pragma unroll
    for (int q = 0; q < 4; ++q)
        T[ty + q * 8][tx] = W[(size_t)(kb + ty + q * 8) * N + nSrc];
    __syncthreads();
#pragma unroll
    for (int q = 0; q < 4; ++q)
        Wt[(size_t)(nb + ty + q * 8) * K + kb + tx] = f2bf(T[tx][ty + q * 8]);
}

// --------------- combined bias: bc[s*1024+n] = (b_qvk[s:].w[:,nSrc]+b[nSrc])*scl
__global__ __launch_bounds__(256) void bias_fold(
    const float* __restrict__ bqvk,
    const float* __restrict__ wq, const float* __restrict__ wk,
    const float* __restrict__ wv,
    const float* __restrict__ bq, const float* __restrict__ bk,
    const float* __restrict__ bv,
    float* __restrict__ bc)
{
    const int n  = blockIdx.x;                 // 0..1023
    const int sl = blockIdx.y;                 // 0..2 (q,k,v)
    const float* w  = sl == 0 ? wq : sl == 1 ? wk : wv;
    const float* bs = sl == 0 ? bq : sl == 1 ? bk : bv;
    const int s = sl << 10;
    const int nSrc = ((n & 63) << 4) + (n >> 6);
    const int t = threadIdx.x;
    float p = 0.f;
    for (int k = t; k < 1024; k += 256)
        p += bqvk[s + k] * w[(size_t)k * 1024 + nSrc];
#pragma unroll
    for (int off = 1; off < 64; off <<= 1) p += __shfl_xor(p, off, 64);
    __shared__ float red[4];
    if ((t & 63) == 0) red[t >> 6] = p;
    __syncthreads();
    if (t == 0) {
        float dot = red[0] + red[1] + red[2] + red[3];
        bc[s + n] = (dot + bs[nSrc]) * (sl == 0 ? 0.125f : 1.0f);
    }
}

// ------- combined qkv weights: Wc[z][n'][k'] = sum_j Ws[z][n'][j]*Wb[k'][z*1024+j]
// Ws = stacked perm'd-transposed w_q/w_k/w_v bf16; Wb = w_qvk bf16 [1024][3072].
// z==0 (q) scaled by 0.125 (QK softmax scale folded, exact pow2).
// 128^2 tile MFMA, grid (8,8,3).
__global__ __launch_bounds__(256) void wcomb_mfma(
    const unsigned short* __restrict__ Ws,
    const unsigned short* __restrict__ Wb,
    unsigned short* __restrict__ Wc)
{
    __shared__ unsigned short At[128 * 32];
    __shared__ unsigned short Bl[128 * 32];
    const int tid = threadIdx.x;
    const int w = tid >> 6, l = tid & 63, g = l >> 4, lr = l & 15;
    const int row0 = blockIdx.y * 128, col0 = blockIdx.x * 128;
    const int z = blockIdx.z;
    const int wr = (w >> 1) * 64, wcq = (w & 1) * 64;
    const float scl = (z == 0) ? 0.125f : 1.0f;

    const unsigned short* A  = Ws + (size_t)z * 1024 * 1024;
    const unsigned short* Bt = Wb + z * 1024;
    unsigned short*       C  = Wc + (size_t)z * 1024 * 1024;

    f32x4 zero = {0.f, 0.f, 0.f, 0.f};
    f32x4 acc[4][4];
#pragma unroll
    for (int m = 0; m < 4; ++m)
#pragma unroll
        for (int n = 0; n < 4; ++n) acc[m][n] = zero;

    const int srow = w * 32 + (l >> 2);
    const int scol = (l & 3) * 8;
    const unsigned short* aS = A + (size_t)(row0 + srow) * 1024 + scol;
    const unsigned short* bS = Bt + (size_t)(col0 + srow) * 3072 + scol;
    unsigned short* aD0 = &At[w * 1024];
    unsigned short* aD1 = &At[w * 1024 + 512];
    unsigned short* bD0 = &Bl[w * 1024];
    unsigned short* bD1 = &Bl[w * 1024 + 512];

    for (int k0 = 0; k0 < 1024; k0 += 32) {
        __syncthreads();
        __builtin_amdgcn_global_load_lds(GLB(aS + k0), LDSP(aD0), 16, 0, 0);
        __builtin_amdgcn_global_load_lds(GLB(aS + (size_t)16 * 1024 + k0), LDSP(aD1), 16, 0, 0);
        __builtin_amdgcn_global_load_lds(GLB(bS + k0), LDSP(bD0), 16, 0, 0);
        __builtin_amdgcn_global_load_lds(GLB(bS + (size_t)16 * 3072 + k0), LDSP(bD1), 16, 0, 0);
        __syncthreads();

        s16x8 a[4], b[4];
#pragma unroll
        for (int m = 0; m < 4; ++m)
            a[m] = *(const s16x8*)&At[(wr + m * 16 + lr) * 32 + g * 8];
#pragma unroll
        for (int n = 0; n < 4; ++n)
            b[n] = *(const s16x8*)&Bl[(wcq + n * 16 + lr) * 32 + g * 8];
#pragma unroll
        for (int m = 0; m < 4; ++m)
#pragma unroll
            for (int n = 0; n < 4; ++n)
                acc[m][n] = __builtin_amdgcn_mfma_f32_16x16x32_bf16(
                    a[m], b[n], acc[m][n], 0, 0, 0);
    }

#pragma unroll
    for (int m = 0; m < 4; ++m)
#pragma unroll
        for (int n = 0; n < 4; ++n)
#pragma unroll
            for (int r = 0; r < 4; ++r) {
                const int row = row0 + wr + m * 16 + g * 4 + r;
                const int col = col0 + wcq + n * 16 + lr;
                C[(size_t)row * 1024 + col] = f2bf(acc[m][n][r] * scl);
            }
}

// ------------- global V transpose: vb[.][ldv] cols->vT[1024][M] -------------
__global__ __launch_bounds__(256) void transpose_v(
    const unsigned short* __restrict__ vb, unsigned short* __restrict__ vt,
    int M, int ldv)
{
    const int T = blockIdx.x * 256 + threadIdx.x;
    const int c  = T & 1023;
    const int r0 = (T >> 10) << 3;
    s16x8 o;
#pragma unroll
    for (int i = 0; i < 8; ++i)
        o[i] = (short)vb[(size_t)(r0 + i) * ldv + c];
    *(s16x8*)&vt[(size_t)c * M + r0] = o;
}

// ------------------------- bf16 MFMA GEMM (m97 structure) ------------------
template <int ACT>
__global__ __launch_bounds__(256) void gemm_bf16(
    const unsigned short* __restrict__ A, int lda,
    const unsigned short* __restrict__ Bt,
    const float* __restrict__ bias,
    unsigned short* __restrict__ C, int ldc,
    int M, int N, int K)
{
    __shared__ unsigned short At[128 * 32];
    __shared__ unsigned short Bl[128 * 32];
    const int tid = threadIdx.x;
    const int w = tid >> 6, l = tid & 63, g = l >> 4, lr = l & 15;
    const int row0 = blockIdx.y * 128, col0 = blockIdx.x * 128;
    const int wr = (w >> 1) * 64, wc = (w & 1) * 64;

    f32x4 zero = {0.f, 0.f, 0.f, 0.f};
    f32x4 acc[4][4];
#pragma unroll
    for (int m = 0; m < 4; ++m)
#pragma unroll
        for (int n = 0; n < 4; ++n) acc[m][n] = zero;

    const int srow = w * 32 + (l >> 2);
    const int scol = (l & 3) * 8;
    const unsigned short* aS = A + (size_t)(row0 + srow) * lda + scol;
    const unsigned short* bS = Bt + (size_t)(col0 + srow) * K + scol;
    unsigned short* aD0 = &At[w * 1024];
    unsigned short* aD1 = &At[w * 1024 + 512];
    unsigned short* bD0 = &Bl[w * 1024];
    unsigned short* bD1 = &Bl[w * 1024 + 512];

    for (int k0 = 0; k0 < K; k0 += 32) {
        __syncthreads();
        __builtin_amdgcn_global_load_lds(GLB(aS + k0), LDSP(aD0), 16, 0, 0);
        __builtin_amdgcn_global_load_lds(GLB(aS + (size_t)16 * lda + k0), LDSP(aD1), 16, 0, 0);
        __builtin_amdgcn_global_load_lds(GLB(bS + k0), LDSP(bD0), 16, 0, 0);
        __builtin_amdgcn_global_load_lds(GLB(bS + (size_t)16 * K + k0), LDSP(bD1), 16, 0, 0);
        __syncthreads();

        s16x8 a[4], b[4];
#pragma unroll
        for (int m = 0; m < 4; ++m)
            a[m] = *(const s16x8*)&At[(wr + m * 16 + lr) * 32 + g * 8];
#pragma unroll
        for (int n = 0; n < 4; ++n)
            b[n] = *(const s16x8*)&Bl[(wc + n * 16 + lr) * 32 + g * 8];
#pragma unroll
        for (int m = 0; m < 4; ++m)
#pragma unroll
            for (int n = 0; n < 4; ++n)
                acc[m][n] = __builtin_amdgcn_mfma_f32_16x16x32_bf16(
                    a[m], b[n], acc[m][n], 0, 0, 0);
    }

    float bv[4];
#pragma unroll
    for (int n = 0; n < 4; ++n) bv[n] = bias[col0 + wc + n * 16 + lr];
#pragma unroll
    for (int m = 0; m < 4; ++m)
#pragma unroll
        for (int n = 0; n < 4; ++n)
#pragma unroll
            for (int r = 0; r < 4; ++r) {
                float vv = acc[m][n][r] + bv[n];
                if (ACT == 1) vv = fminf(fmaxf(vv, 0.f), 6.f);
                const int row = row0 + wr + m * 16 + g * 4 + r;
                const int col = col0 + wc + n * 16 + lr;
                C[(size_t)row * ldc + col] = f2bf(vv);
            }
}

// ------------------------- flash attention, bf16 MFMA ----------------------
// qkv: [M][ldq] bf16, cols 0-1023 = q (pre-scaled by 0.125), 1024-2047 = k,
// both head-contiguous.  vt: [1024][M] bf16 (V^T).
__global__ __launch_bounds__(256) void attn_mfma(
    const unsigned short* __restrict__ qkv,
    const unsigned short* __restrict__ vt,
    unsigned short* __restrict__ vh, int M, int ldq)
{
    __shared__ unsigned short Kt[64 * 64];
    __shared__ unsigned short Vl[64 * 64];
    __shared__ unsigned short Pt[4][16 * 64];

    const int tid = threadIdx.x, w = tid >> 6, l = tid & 63;
    const int g = l >> 4, lr = l & 15;
    const int qt = blockIdx.x, h = blockIdx.y, nb = blockIdx.z;

    const unsigned short* qB = qkv + (size_t)nb * SEQ * ldq + h * 64;
    const unsigned short* kB = qkv + (size_t)nb * SEQ * ldq + 1024 + h * 64;
    const unsigned short* vB = vt + (size_t)h * 64 * M + nb * SEQ;

    s16x8 qa0, qa1;
    {
        const unsigned short* qp = qB + (size_t)(qt * 64 + w * 16 + lr) * ldq + g * 8;
        qa0 = *(const s16x8*)qp;
        qa1 = *(const s16x8*)(qp + 32);
    }

    f32x4 zero = {0.f, 0.f, 0.f, 0.f};
    f32x4 Oc[4];
#pragma unroll
    for (int nd = 0; nd < 4; ++nd) Oc[nd] = zero;
    float mrun[4], lrun[4];
#pragma unroll
    for (int r = 0; r < 4; ++r) { mrun[r] = -3.0e38f; lrun[r] = 0.f; }

    const int srow = w * 16 + (l >> 3);
    const int scol = (((l & 7) * 16) ^ (((l >> 3) & 7) << 4)) >> 1;

    for (int kt = 0; kt < 16; ++kt) {
        __syncthreads();
        const unsigned short* ks0 = kB + (size_t)(kt * 64 + srow) * ldq + scol;
        __builtin_amdgcn_global_load_lds(GLB(ks0), LDSP(&Kt[w * 1024]), 16, 0, 0);
        __builtin_amdgcn_global_load_lds(GLB(ks0 + (size_t)8 * ldq),
                                         LDSP(&Kt[w * 1024 + 512]), 16, 0, 0);
        const unsigned short* vs0 = vB + (size_t)srow * M + kt * 64 + scol;
        __builtin_amdgcn_global_load_lds(GLB(vs0), LDSP(&Vl[w * 1024]), 16, 0, 0);
        __builtin_amdgcn_global_load_lds(GLB(vs0 + (size_t)8 * M),
                                         LDSP(&Vl[w * 1024 + 512]), 16, 0, 0);
        __syncthreads();

        // S = Q K^T (q pre-scaled by 0.125 at weight-combine time)
        f32x4 sc[4];
#pragma unroll
        for (int nk = 0; nk < 4; ++nk) {
            const int row = nk * 16 + lr;
            const int swz = (row & 7) << 4;
            const s16x8 b0 = *(const s16x8*)&Kt[row * 64 + (((g * 16) ^ swz) >> 1)];
            const s16x8 b1 = *(const s16x8*)&Kt[row * 64 + (((g * 16 + 64) ^ swz) >> 1)];
            sc[nk] = __builtin_amdgcn_mfma_f32_16x16x32_bf16(qa0, b0, zero, 0, 0, 0);
            sc[nk] = __builtin_amdgcn_mfma_f32_16x16x32_bf16(qa1, b1, sc[nk], 0, 0, 0);
        }

        float corr[4];
#pragma unroll
        for (int r = 0; r < 4; ++r) {
            float s0 = sc[0][r], s1 = sc[1][r], s2 = sc[2][r], s3 = sc[3][r];
            float mt = fmaxf(fmaxf(s0, s1), fmaxf(s2, s3));
            mt = fmaxf(mt, __shfl_xor(mt, 1, 64));
            mt = fmaxf(mt, __shfl_xor(mt, 2, 64));
            mt = fmaxf(mt, __shfl_xor(mt, 4, 64));
            mt = fmaxf(mt, __shfl_xor(mt, 8, 64));
            const float mn = fmaxf(mrun[r], mt);
            corr[r] = __expf(mrun[r] - mn);
            mrun[r] = mn;
            float p0 = __expf(s0 - mn), p1 = __expf(s1 - mn);
            float p2 = __expf(s2 - mn), p3 = __expf(s3 - mn);
            float ps = p0 + p1 + p2 + p3;
            ps += __shfl_xor(ps, 1, 64);
            ps += __shfl_xor(ps, 2, 64);
            ps += __shfl_xor(ps, 4, 64);
            ps += __shfl_xor(ps, 8, 64);
            lrun[r] = lrun[r] * corr[r] + ps;

            // P -> bf16 via packed convert (bit-identical RNE, 2 ops vs ~18)
            unsigned pk01, pk23;
            asm("v_cvt_pk_bf16_f32 %0, %1, %2" : "=v"(pk01) : "v"(p0), "v"(p1));
            asm("v_cvt_pk_bf16_f32 %0, %1, %2" : "=v"(pk23) : "v"(p2), "v"(p3));
            const int qrow = g * 4 + r;
            const int pswz = (qrow & 7) << 4;
            Pt[w][qrow * 64 + (((2 * (0 * 16 + lr)) ^ pswz) >> 1)] = (unsigned short)pk01;
            Pt[w][qrow * 64 + (((2 * (1 * 16 + lr)) ^ pswz) >> 1)] = (unsigned short)(pk01 >> 16);
            Pt[w][qrow * 64 + (((2 * (2 * 16 + lr)) ^ pswz) >> 1)] = (unsigned short)pk23;
            Pt[w][qrow * 64 + (((2 * (3 * 16 + lr)) ^ pswz) >> 1)] = (unsigned short)(pk23 >> 16);
        }
#pragma unroll
        for (int nd = 0; nd < 4; ++nd)
#pragma unroll
            for (int r = 0; r < 4; ++r) Oc[nd][r] *= corr[r];

#pragma unroll
        for (int kk = 0; kk < 2; ++kk) {
            const int prswz = (lr & 7) << 4;
            const s16x8 pa = *(const s16x8*)
                &Pt[w][lr * 64 + (((g * 16 + kk * 64) ^ prswz) >> 1)];
#pragma unroll
            for (int nd = 0; nd < 4; ++nd) {
                const int row = nd * 16 + lr;
                const int vswz = (row & 7) << 4;
                const s16x8 bv = *(const s16x8*)
                    &Vl[row * 64 + (((g * 16 + kk * 64) ^ vswz) >> 1)];
                Oc[nd] = __builtin_amdgcn_mfma_f32_16x16x32_bf16(pa, bv, Oc[nd], 0, 0, 0);
            }
        }
    }

    float inv[4];
#pragma unroll
    for (int r = 0; r < 4; ++r) inv[r] = 1.0f / lrun[r];
#pragma unroll
    for (int nd = 0; nd < 4; ++nd)
#pragma unroll
        for (int r = 0; r < 4; ++r) {
            const int qrow = g * 4 + r;
            const int pswz = (qrow & 7) << 4;
            Pt[w][qrow * 64 + (((2 * (nd * 16 + lr)) ^ pswz) >> 1)] =
                f2bf(Oc[nd][r] * inv[r]);
        }
    const int rr = l >> 2;
    unsigned short* dst = vh + (size_t)(nb * SEQ + qt * 64 + w * 16 + rr) * D_MODEL + h * 64;
#pragma unroll
    for (int hh = 0; hh < 2; ++hh) {
        const int sb = (l & 3) * 32 + hh * 16;
        s16x8 o = *(const s16x8*)&Pt[w][rr * 64 + ((sb ^ ((rr & 7) << 4)) >> 1)];
        *(s16x8*)(dst + (sb >> 1)) = o;
    }
}

// ------------------------------ LayerNorm (bf16 in) ------------------------
template <int OUTF32>
__global__ __launch_bounds__(256) void ln_bf16(
    const unsigned short* __restrict__ x,
    const float* __restrict__ gg,
    const float* __restrict__ bb,
    void* __restrict__ outp)
{
    const int row = blockIdx.x, tid = threadIdx.x;
    u16x4 xv = *(const u16x4*)&x[(size_t)row * 1024 + tid * 4];
    float f0 = bf2f(xv[0]), f1 = bf2f(xv[1]), f2 = bf2f(xv[2]), f3 = bf2f(xv[3]);
    float s  = f0 + f1 + f2 + f3;
    float sq = f0 * f0 + f1 * f1 + f2 * f2 + f3 * f3;
#pragma unroll
    for (int off = 1; off < 64; off <<= 1) {
        s  += __shfl_xor(s,  off, 64);
        sq += __shfl_xor(sq, off, 64);
    }
    __shared__ float ls[4], lq[4];
    const int wave = tid >> 6;
    if ((tid & 63) == 0) { ls[wave] = s; lq[wave] = sq; }
    __syncthreads();
    s  = ls[0] + ls[1] + ls[2] + ls[3];
    sq = lq[0] + lq[1] + lq[2] + lq[3];
    const float mu  = s * (1.0f / 1024.0f);
    const float var = sq * (1.0f / 1024.0f) - mu * mu;
    const float rs  = rsqrtf(var + 1e-5f);
    const float4 gv = ((const float4*)gg)[tid];
    const float4 bv = ((const float4*)bb)[tid];
    float o0 = (f0 - mu) * rs * gv.x + bv.x;
    float o1 = (f1 - mu) * rs * gv.y + bv.y;
    float o2 = (f2 - mu) * rs * gv.z + bv.z;
    float o3 = (f3 - mu) * rs * gv.w + bv.w;
    if (OUTF32) {
        float4 o; o.x = o0; o.y = o1; o.z = o2; o.w = o3;
        ((float4*)outp)[(size_t)row * 256 + tid] = o;
    } else {
        u16x4 o;
        o[0] = f2bf(o0); o[1] = f2bf(o1); o[2] = f2bf(o2); o[3] = f2bf(o3);
        ((u16x4*)outp)[(size_t)row * 256 + tid] = o;
    }
}

// ------------------------------- launch ------------------------------------
extern "C" void kernel_launch(void* const* d_in, const int* in_sizes, int n_in,
                              void* d_out, int out_size, void* d_ws, size_t ws_size,
                              hipStream_t stream)
{
    const float* x     = (const float*)d_in[0];
    const float* w_qvk = (const float*)d_in[1];
    const float* b_qvk = (const float*)d_in[2];
    const float* w_q   = (const float*)d_in[3];
    const float* b_q   = (const float*)d_in[4];
    const float* w_k   = (const float*)d_in[5];
    const float* b_k   = (const float*)d_in[6];
    const float* w_v   = (const float*)d_in[7];
    const float* b_v   = (const float*)d_in[8];
    const float* w_o   = (const float*)d_in[9];
    const float* b_o   = (const float*)d_in[10];
    const float* ln1_g = (const float*)d_in[11];
    const float* ln1_b = (const float*)d_in[12];
    const float* w1    = (const float*)d_in[13];
    const float* b1    = (const float*)d_in[14];
    const float* w2    = (const float*)d_in[15];
    const float* b2    = (const float*)d_in[16];
    const float* ln2_g = (const float*)d_in[17];
    const float* ln2_b = (const float*)d_in[18];
    float* out = (float*)d_out;

    const int nbatch = in_sizes[0] / (SEQ * D_MODEL);   // 8
    const int M = nbatch * SEQ;                          // 8192

    char* ws = (char*)d_ws;
    size_t off = 0;
    auto alloc = [&](size_t bytes) { size_t o = off; off += (bytes + 255) & ~(size_t)255; return o; };
    const size_t XB    = alloc((size_t)M * 1024 * 2);       // 16 MiB
    const size_t QKVB  = alloc((size_t)M * 3072 * 2);       // 48 MiB
    const size_t VT    = alloc((size_t)M * 1024 * 2);       // 16 MiB
    const size_t VH    = alloc((size_t)M * 1024 * 2);       // 16 MiB
    const size_t WQVKB = alloc((size_t)1024 * 3072 * 2);    //  6 MiB
    const size_t WSUB  = alloc((size_t)3 * 1024 * 1024 * 2);//  6 MiB
    const size_t WC    = alloc((size_t)3 * 1024 * 1024 * 2);//  6 MiB
    const size_t WO    = alloc((size_t)1024 * 1024 * 2);
    const size_t W1    = alloc((size_t)2048 * 1024 * 2);
    const size_t W2    = alloc((size_t)2048 * 1024 * 2);
    const size_t BC    = alloc(3072 * 4);
    // aliases into dead regions (lifetimes verified):
    const size_t ATTP = QKVB;                                // [0:16M) of qkvb
    const size_t ATTB = QKVB + (size_t)M * 1024 * 2;         // [16M:32M)
    const size_t OUTP = QKVB + (size_t)M * 2048 * 2;         // [32M:48M)
    const size_t HID  = VT;                                  // VT+VH = 32 MiB

    unsigned short* xb    = (unsigned short*)(ws + XB);
    unsigned short* qkvb  = (unsigned short*)(ws + QKVB);
    unsigned short* vtb   = (unsigned short*)(ws + VT);
    unsigned short* vhb   = (unsigned short*)(ws + VH);
    unsigned short* wqvkb = (unsigned short*)(ws + WQVKB);
    unsigned short* wsub  = (unsigned short*)(ws + WSUB);
    unsigned short* wc    = (unsigned short*)(ws + WC);
    unsigned short* wo    = (unsigned short*)(ws + WO);
    unsigned short* wt1   = (unsigned short*)(ws + W1);
    unsigned short* wt2   = (unsigned short*)(ws + W2);
    float*          bc    = (float*)(ws + BC);
    unsigned short* attp  = (unsigned short*)(ws + ATTP);
    unsigned short* attb  = (unsigned short*)(ws + ATTB);
    unsigned short* hid   = (unsigned short*)(ws + HID);
    unsigned short* outp  = (unsigned short*)(ws + OUTP);

    const dim3 tb(32, 8);

    // casts + weight prep
    cast_f32_bf16<<<(M * 1024 / 4 + 255) / 256, 256, 0, stream>>>(x, xb, M * 1024 / 4);
    cast_f32_bf16<<<(1024 * 3072 / 4 + 255) / 256, 256, 0, stream>>>(w_qvk, wqvkb, 1024 * 3072 / 4);
    wt_cast<true ><<<dim3(32, 32), tb, 0, stream>>>(w_q, wsub + 0 * 1024 * 1024, 1024, 1024);
    wt_cast<true ><<<dim3(32, 32), tb, 0, stream>>>(w_k, wsub + 1 * 1024 * 1024, 1024, 1024);
    wt_cast<true ><<<dim3(32, 32), tb, 0, stream>>>(w_v, wsub + 2 * 1024 * 1024, 1024, 1024);
    wt_cast<false><<<dim3(32, 32), tb, 0, stream>>>(w_o, wo, 1024, 1024);
    wt_cast<false><<<dim3(64, 32), tb, 0, stream>>>(w1, wt1, 1024, 2048);
    wt_cast<false><<<dim3(32, 64), tb, 0, stream>>>(w2, wt2, 2048, 1024);
    bias_fold<<<dim3(1024, 3), 256, 0, stream>>>(b_qvk, w_q, w_k, w_v,
                                                 b_q, b_k, b_v, bc);
    wcomb_mfma<<<dim3(8, 8, 3), 256, 0, stream>>>(wsub, wqvkb, wc);

    // fused qkv projection: qkvb[M][3072] = xb @ Wc^T + bc  (q pre-scaled)
    gemm_bf16<0><<<dim3(24, M / 128), 256, 0, stream>>>(
        xb, 1024, wc, bc, qkvb, 3072, M, 3072, 1024);

    transpose_v<<<(M / 8) * 1024 / 256, 256, 0, stream>>>(qkvb + 2048, vtb, M, 3072);
    attn_mfma<<<dim3(SEQ / 64, NHEAD, nbatch), 256, 0, stream>>>(qkvb, vtb, vhb, M, 3072);

    gemm_bf16<0><<<dim3(8, M / 128), 256, 0, stream>>>(
        vhb, 1024, wo, b_o, attp, 1024, M, 1024, 1024);
    ln_bf16<0><<<M, 256, 0, stream>>>(attp, ln1_g, ln1_b, attb);

    gemm_bf16<1><<<dim3(16, M / 128), 256, 0, stream>>>(
        attb, 1024, wt1, b1, hid, 2048, M, 2048, 1024);
    gemm_bf16<0><<<dim3(8, M / 128), 256, 0, stream>>>(
        hid, 2048, wt2, b2, outp, 1024, M, 1024, 2048);
    ln_bf16<1><<<M, 256, 0, stream>>>(outp, ln2_g, ln2_b, out);
}